// Round 8
// baseline (735.040 us; speedup 1.0000x reference)
//
#include <hip/hip_runtime.h>
#include <stdint.h>

// ---------- types ----------
typedef __attribute__((ext_vector_type(4))) float f32x4;
typedef __attribute__((ext_vector_type(8))) short bf16x8;
typedef __attribute__((ext_vector_type(4))) unsigned int u32x4;

__device__ __forceinline__ short f2bf(float x) {
  unsigned int u = __builtin_bit_cast(unsigned int, x);
  unsigned int r = (u + 0x7fffu + ((u >> 16) & 1u)) >> 16;
  return (short)r;
}
__device__ __forceinline__ float bf2f(short s) {
  unsigned int u = ((unsigned int)(unsigned short)s) << 16;
  return __builtin_bit_cast(float, u);
}
__device__ __forceinline__ unsigned pkbf(float lo, float hi) {
  unsigned r;
  asm("v_cvt_pk_bf16_f32 %0, %1, %2" : "=v"(r) : "v"(lo), "v"(hi));
  return r;
}

__device__ __forceinline__ void gload_lds16(const void* g, void* l) {
  __builtin_amdgcn_global_load_lds(
      (const __attribute__((address_space(1))) void*)g,
      (__attribute__((address_space(3))) void*)l, 16, 0, 0);
}

// ---------- fp32 -> bf16 converts, up to 5 tensors in one launch ----------
__global__ __launch_bounds__(256) void cvt5(const float* __restrict__ a,
                                            const float* __restrict__ b,
                                            const float* __restrict__ c,
                                            const float* __restrict__ d,
                                            const float* __restrict__ e,
                                            short* __restrict__ oa,
                                            short* __restrict__ ob,
                                            short* __restrict__ oc,
                                            short* __restrict__ od,
                                            short* __restrict__ oe, int n) {
  int y = blockIdx.y;
  const float* in = (y == 0) ? a : (y == 1) ? b : (y == 2) ? c : (y == 3) ? d : e;
  short* out = (y == 0) ? oa : (y == 1) ? ob : (y == 2) ? oc : (y == 3) ? od : oe;
  int idx = blockIdx.x * blockDim.x + threadIdx.x;
  int stride = gridDim.x * blockDim.x;
  for (int i = idx * 4; i < n; i += stride * 4) {
    float4 v = *(const float4*)(in + i);
    short4 o;
    o.x = f2bf(v.x); o.y = f2bf(v.y); o.z = f2bf(v.z); o.w = f2bf(v.w);
    *(short4*)(out + i) = o;
  }
}

__global__ __launch_bounds__(256) void cvt_bf16(const float* __restrict__ in,
                                                short* __restrict__ out, int n) {
  int idx = blockIdx.x * blockDim.x + threadIdx.x;
  int stride = gridDim.x * blockDim.x;
  for (int i = idx * 4; i < n; i += stride * 4) {
    float4 v = *(const float4*)(in + i);
    short4 o;
    o.x = f2bf(v.x); o.y = f2bf(v.y); o.z = f2bf(v.z); o.w = f2bf(v.w);
    *(short4*)(out + i) = o;
  }
}

// ---------- RoPE table ----------
__global__ __launch_bounds__(256) void rope_table_k(float2* __restrict__ tab) {
  int idx = blockIdx.x * 256 + threadIdx.x;  // 131072 total
  int s = idx >> 6, j = idx & 63;
  float invf = powf(10000.0f, -((float)j) / 64.0f);
  float a = (float)s * invf;
  tab[idx] = make_float2(cosf(a), sinf(a));
}

// ---------- RoPE apply in-place; Q scaled by log2(e)/sqrt(128) ----------
__global__ __launch_bounds__(256) void rope_apply_k(short* __restrict__ Qb,
                                                    short* __restrict__ Kb,
                                                    const float2* __restrict__ tab) {
  bool isK = (blockIdx.y != 0);
  short* base = isK ? Kb : Qb;
  float post = isK ? 1.0f : (0.08838834764831845f * 1.4426950408889634f);
  int token = blockIdx.x;
  int s = token & 2047;
  short* rowp = base + (size_t)token * 4096;
  const float2* trow = tab + s * 64;
  for (int u = threadIdx.x; u < 512; u += 256) {
    int h = u >> 4;
    int d0 = (u & 15) * 4;
    short* p1 = rowp + h * 128 + d0;
    short* p2 = p1 + 64;
    short4 a = *(short4*)p1, b = *(short4*)p2;
    short4 ra, rb;
#pragma unroll
    for (int j = 0; j < 4; ++j) {
      short aj = (&a.x)[j], bj = (&b.x)[j];
      float qa = bf2f(aj), qb = bf2f(bj);
      float2 cs = trow[d0 + j];
      (&ra.x)[j] = f2bf((qa * cs.x - qb * cs.y) * post);
      (&rb.x)[j] = f2bf((qb * cs.x + qa * cs.y) * post);
    }
    *(short4*)p1 = ra;
    *(short4*)p2 = rb;
  }
}

// ---------- GEMM 256x256 tile, BK=64, 8-phase interleave, counted vmcnt (R7-proven) ----------
template <int MODE>
__global__ __launch_bounds__(512) void gemm8p(const short* __restrict__ A,
                                              const short* __restrict__ Bw,
                                              void* __restrict__ out) {
  __shared__ __attribute__((aligned(16))) short smem[2 * 32768];
  int wg = blockIdx.x;           // 256 blocks = 1 per CU
  int xcd = wg & 7, ii = wg >> 3;
  int by = xcd * 2 + (ii >> 4);
  int bx = ii & 15;
  int tid = threadIdx.x;
  int w = tid >> 6, lane = tid & 63;
  int l16 = lane & 15, l4 = lane >> 4;
  int wm = w >> 2, wn = w & 3;

  f32x4 acc[8][4] = {};

  const short* Ab = A + (size_t)(by * 256) * 4096;
  const short* Bb = Bw + (size_t)(bx * 256) * 4096;

  auto STAGE_MAT = [&](int kt, int isB) {
    const short* src = isB ? Bb : Ab;
    int ob = (kt & 1) * 32768 + isB * 16384;
#pragma unroll
    for (int j = 0; j < 4; ++j) {
      int c = j * 512 + tid;
      int row = c >> 3;
      int sc = (c & 7) ^ (row & 7);
      gload_lds16(src + (size_t)row * 4096 + kt * 64 + sc * 8, &smem[ob + c * 8]);
    }
  };

  bf16x8 bfr[4];
  auto PHASE = [&](int ob, int kk, int mh, bool loadB) {
    const short* lA = &smem[ob];
    const short* lB = &smem[ob + 16384];
    if (loadB) {
#pragma unroll
      for (int nf = 0; nf < 4; ++nf) {
        int row = wn * 64 + nf * 16 + l16;
        int phys = (kk * 4 + l4) ^ (row & 7);
        bfr[nf] = *(const bf16x8*)&lB[row * 64 + phys * 8];
      }
    }
    bf16x8 af[4];
#pragma unroll
    for (int mf = 0; mf < 4; ++mf) {
      int row = wm * 128 + mh * 64 + mf * 16 + l16;
      int phys = (kk * 4 + l4) ^ (row & 7);
      af[mf] = *(const bf16x8*)&lA[row * 64 + phys * 8];
    }
    __builtin_amdgcn_s_setprio(1);
#pragma unroll
    for (int mf = 0; mf < 4; ++mf)
#pragma unroll
      for (int nf = 0; nf < 4; ++nf)
        acc[mh * 4 + mf][nf] =
            __builtin_amdgcn_mfma_f32_16x16x32_bf16(af[mf], bfr[nf], acc[mh * 4 + mf][nf], 0, 0, 0);
    __builtin_amdgcn_s_setprio(0);
    __builtin_amdgcn_s_barrier();
    asm volatile("" ::: "memory");
  };

  STAGE_MAT(0, 0);
  STAGE_MAT(0, 1);
  asm volatile("s_waitcnt vmcnt(0)" ::: "memory");
  __builtin_amdgcn_s_barrier();
  asm volatile("" ::: "memory");

  const int b0 = 0, b1 = 32768;
  for (int i = 0; i < 32; ++i) {
    int kt1 = 2 * i + 1;
    // p0
    STAGE_MAT(kt1, 0);
    asm volatile("s_waitcnt vmcnt(4)" ::: "memory");
    __builtin_amdgcn_s_barrier();
    asm volatile("" ::: "memory");
    PHASE(b0, 0, 0, true);
    // p1
    STAGE_MAT(kt1, 1);
    PHASE(b0, 0, 1, false);
    // p2
    PHASE(b0, 1, 0, true);
    // p3
    PHASE(b0, 1, 1, false);
    // p4
    if (i + 1 < 32) {
      STAGE_MAT(2 * i + 2, 0);
      asm volatile("s_waitcnt vmcnt(4)" ::: "memory");
    } else {
      asm volatile("s_waitcnt vmcnt(0)" ::: "memory");
    }
    __builtin_amdgcn_s_barrier();
    asm volatile("" ::: "memory");
    PHASE(b1, 0, 0, true);
    // p5
    if (i + 1 < 32) STAGE_MAT(2 * i + 2, 1);
    PHASE(b1, 0, 1, false);
    // p6
    PHASE(b1, 1, 0, true);
    // p7
    PHASE(b1, 1, 1, false);
  }

  int orow0 = by * 256 + wm * 128;
  int ocol0 = bx * 256 + wn * 64;
#pragma unroll
  for (int mf = 0; mf < 8; ++mf)
#pragma unroll
    for (int nf = 0; nf < 4; ++nf)
#pragma unroll
      for (int k = 0; k < 4; ++k) {
        int r = orow0 + mf * 16 + l4 * 4 + k;
        int c = ocol0 + nf * 16 + l16;
        float v = acc[mf][nf][k];
        if constexpr (MODE == 0) {
          ((short*)out)[(size_t)r * 4096 + c] = f2bf(v);
        } else if constexpr (MODE == 1) {
          ((float*)out)[(size_t)r * 4096 + c] = v;
        } else {
          int bb = r >> 11, ss = r & 2047;
          int h = c >> 7, d = c & 127;
          ((short*)out)[(((size_t)((bb * 32 + h) * 128 + d)) << 11) + ss] = f2bf(v);
        }
      }
}

// ---------- Flash attention (R5 structure, clean regalloc): K dbuf + V single buf (48KB LDS
// -> 3 blocks/CU), raw s_barrier + counted vmcnt ledger (no full drains in steady state).
// Q pre-scaled by log2e/sqrt(128). Q,K token-major [4096][4096], Vt [64][128][2048].
__global__ __launch_bounds__(256) void attn_k(const short* __restrict__ Qb,
                                              const short* __restrict__ Kb,
                                              const short* __restrict__ Vt,
                                              short* __restrict__ AO) {
  __shared__ __attribute__((aligned(16))) short smem[24576];  // K0 8192 | K1 8192 | V 8192 (shorts)
  int p = blockIdx.x;  // qt-major LPT: longest first
  int bh = p & 63;
  int qt = 15 - (p >> 6);
  int b = bh >> 5, h = bh & 31;
  int tid = threadIdx.x, w = tid >> 6, lane = tid & 63;
  int l16 = lane & 15, l4 = lane >> 4;

  const int nt = 2 * qt + 2;  // nt >= 2 always
  const int qbase = qt * 128 + w * 32;

  bf16x8 qf[2][4];
  {
    const short* Qg = Qb + (size_t)(b * 2048 + qbase + l16) * 4096 + h * 128 + l4 * 8;
#pragma unroll
    for (int mg = 0; mg < 2; ++mg)
#pragma unroll
      for (int kk = 0; kk < 4; ++kk)
        qf[mg][kk] = *(const bf16x8*)(Qg + (size_t)mg * 16 * 4096 + kk * 32);
  }

  f32x4 oacc[2][8] = {};
  float mrun[2] = {-1e30f, -1e30f}, lsum[2] = {0.f, 0.f};

  const short* Kbase = Kb + (size_t)(b * 2048) * 4096 + h * 128;
  const short* Vbase = Vt + (size_t)bh * 128 * 2048;

  const int srowK = l4, skbK = l16;
  const int srowV = lane >> 3, skbV = lane & 7;

  auto STAGE_K = [&](int t, int sel) {  // 4 loads/thread
    short* lK = &smem[sel * 8192];
#pragma unroll
    for (int ii = 0; ii < 4; ++ii) {
      int s = w * 4 + ii;
      int rowK = s * 4 + srowK;
      int srcK = skbK ^ (rowK & 15);
      gload_lds16(Kbase + (size_t)(t * 64 + rowK) * 4096 + srcK * 8, &lK[s * 512]);
    }
  };
  auto STAGE_V = [&](int t) {  // 4 loads/thread
    short* lV = &smem[16384];
#pragma unroll
    for (int ii = 0; ii < 4; ++ii) {
      int s = w * 4 + ii;
      int rowV = s * 8 + srowV;
      int srcV = skbV ^ (rowV & 7);
      gload_lds16(Vbase + (size_t)rowV * 2048 + t * 64 + srcV * 8, &lV[s * 512]);
    }
  };

  // prologue: issue V(0), K(0), K(1); confirm V(0)+K(0) (leave K(1) flying)
  STAGE_V(0);
  STAGE_K(0, 0);
  STAGE_K(1, 1);
  asm volatile("s_waitcnt vmcnt(4)" ::: "memory");
  __builtin_amdgcn_s_barrier();
  asm volatile("" ::: "memory");

  const int src0 = l16 | ((2 * (l4 & 1)) << 4);
  const int src1 = src0 | 16;
  const bool hiA = (l4 >> 1) != 0;

  for (int t = 0; t < nt; ++t) {
    const short* lK = &smem[(t & 1) * 8192];
    const short* lV = &smem[16384];
    bool skip = (t * 64 > qbase + 31);  // tile fully above this wave's diagonal

    f32x4 sacc[2][4] = {};
    if (!skip) {
#pragma unroll
      for (int kk = 0; kk < 4; ++kk) {
#pragma unroll
        for (int n4 = 0; n4 < 4; ++n4) {
          int row = n4 * 16 + l16;
          int phys = (kk * 4 + l4) ^ (row & 15);
          bf16x8 kf = *(const bf16x8*)&lK[row * 128 + phys * 8];
          sacc[0][n4] = __builtin_amdgcn_mfma_f32_16x16x32_bf16(kf, qf[0][kk], sacc[0][n4], 0, 0, 0);
          sacc[1][n4] = __builtin_amdgcn_mfma_f32_16x16x32_bf16(kf, qf[1][kk], sacc[1][n4], 0, 0, 0);
        }
      }

      if (t * 64 + 63 > qbase) {  // diagonal zone: causal mask
#pragma unroll
        for (int mg = 0; mg < 2; ++mg) {
          int q = qbase + mg * 16 + l16;
#pragma unroll
          for (int n4 = 0; n4 < 4; ++n4)
#pragma unroll
            for (int i = 0; i < 4; ++i) {
              int kv = t * 64 + n4 * 16 + l4 * 4 + i;
              if (kv > q) sacc[mg][n4][i] = -1e30f;
            }
        }
      }

      // online softmax in log2 domain, defer-max (THR=8 -> P <= 256)
#pragma unroll
      for (int mg = 0; mg < 2; ++mg) {
        float v0 = fmaxf(fmaxf(sacc[mg][0][0], sacc[mg][0][1]), fmaxf(sacc[mg][0][2], sacc[mg][0][3]));
        float v1 = fmaxf(fmaxf(sacc[mg][1][0], sacc[mg][1][1]), fmaxf(sacc[mg][1][2], sacc[mg][1][3]));
        float v2 = fmaxf(fmaxf(sacc[mg][2][0], sacc[mg][2][1]), fmaxf(sacc[mg][2][2], sacc[mg][2][3]));
        float v3 = fmaxf(fmaxf(sacc[mg][3][0], sacc[mg][3][1]), fmaxf(sacc[mg][3][2], sacc[mg][3][3]));
        float vm = fmaxf(fmaxf(v0, v1), fmaxf(v2, v3));
        vm = fmaxf(vm, __shfl_xor(vm, 16));
        vm = fmaxf(vm, __shfl_xor(vm, 32));
        float mn = mrun[mg];
        if (!__all(vm - mn <= 8.0f)) {
          float mnew = fmaxf(mn, vm);
          float fsc = __builtin_amdgcn_exp2f(mn - mnew);
          mrun[mg] = mnew;
          lsum[mg] *= fsc;
#pragma unroll
          for (int dg = 0; dg < 8; ++dg) oacc[mg][dg] *= fsc;
          mn = mnew;
        }
        float psum = 0.f;
#pragma unroll
        for (int n4 = 0; n4 < 4; ++n4)
#pragma unroll
          for (int i = 0; i < 4; ++i) {
            float e = __builtin_amdgcn_exp2f(sacc[mg][n4][i] - mn);
            sacc[mg][n4][i] = e;
            psum += e;
          }
        psum += __shfl_xor(psum, 16);
        psum += __shfl_xor(psum, 32);
        lsum[mg] += psum;
      }
    }

    // V(t) ready: confirm the 4 V-loads (K(t+1)'s 4 may stay in flight)
    if (t == nt - 1)
      asm volatile("s_waitcnt vmcnt(0)" ::: "memory");
    else
      asm volatile("s_waitcnt vmcnt(4)" ::: "memory");
    __builtin_amdgcn_s_barrier();
    asm volatile("" ::: "memory");

    if (!skip) {
      bf16x8 pb[2][2];
#pragma unroll
      for (int mg = 0; mg < 2; ++mg)
#pragma unroll
        for (int c = 0; c < 2; ++c) {
          unsigned pk0h0 = pkbf(sacc[mg][2 * c][0], sacc[mg][2 * c][1]);
          unsigned pk0h1 = pkbf(sacc[mg][2 * c][2], sacc[mg][2 * c][3]);
          unsigned pk1h0 = pkbf(sacc[mg][2 * c + 1][0], sacc[mg][2 * c + 1][1]);
          unsigned pk1h1 = pkbf(sacc[mg][2 * c + 1][2], sacc[mg][2 * c + 1][3]);
          unsigned s00 = __shfl((int)pk0h0, src0), s10 = __shfl((int)pk1h0, src0);
          unsigned s01 = __shfl((int)pk0h1, src0), s11 = __shfl((int)pk1h1, src0);
          unsigned t00 = __shfl((int)pk0h0, src1), t10 = __shfl((int)pk1h0, src1);
          unsigned t01 = __shfl((int)pk0h1, src1), t11 = __shfl((int)pk1h1, src1);
          u32x4 uw;
          uw[0] = hiA ? s10 : s00;
          uw[1] = hiA ? s11 : s01;
          uw[2] = hiA ? t10 : t00;
          uw[3] = hiA ? t11 : t01;
          pb[mg][c] = __builtin_bit_cast(bf16x8, uw);
        }

#pragma unroll
      for (int c = 0; c < 2; ++c)
#pragma unroll
        for (int dg = 0; dg < 8; ++dg) {
          int d = dg * 16 + l16;
          int phys = (c * 4 + l4) ^ (d & 7);
          bf16x8 vf = *(const bf16x8*)&lV[d * 64 + phys * 8];
          oacc[0][dg] = __builtin_amdgcn_mfma_f32_16x16x32_bf16(vf, pb[0][c], oacc[0][dg], 0, 0, 0);
          oacc[1][dg] = __builtin_amdgcn_mfma_f32_16x16x32_bf16(vf, pb[1][c], oacc[1][dg], 0, 0, 0);
        }
    }

    // all waves done reading V(t) and K(t): safe to overwrite
    __builtin_amdgcn_s_barrier();
    asm volatile("" ::: "memory");
    if (t + 1 < nt) STAGE_V(t + 1);           // issue V first (ledger order)
    if (t + 2 < nt) STAGE_K(t + 2, t & 1);
    // confirm K(t+1) for next iteration's QK^T
    if (t + 2 < nt)
      asm volatile("s_waitcnt vmcnt(8)" ::: "memory");
    else if (t + 1 < nt)
      asm volatile("s_waitcnt vmcnt(4)" ::: "memory");
    __builtin_amdgcn_s_barrier();
    asm volatile("" ::: "memory");
  }

  // epilogue: normalize, transpose O^T -> O via per-wave LDS region, coalesced store
  short* reg = &smem[w * 4096];
  float rls0 = 1.0f / lsum[0], rls1 = 1.0f / lsum[1];
#pragma unroll
  for (int mg = 0; mg < 2; ++mg) {
    float rls = mg ? rls1 : rls0;
    int qloc = mg * 16 + l16;
#pragma unroll
    for (int dg = 0; dg < 8; ++dg) {
      unsigned u0 = pkbf(oacc[mg][dg][0] * rls, oacc[mg][dg][1] * rls);
      unsigned u1 = pkbf(oacc[mg][dg][2] * rls, oacc[mg][dg][3] * rls);
      int c16 = dg * 2 + (l4 >> 1);
      int phys = c16 ^ (qloc & 7);
      int sidx = qloc * 128 + phys * 8 + (l4 & 1) * 4;
      *(uint2*)&reg[sidx] = make_uint2(u0, u1);
    }
  }
#pragma unroll
  for (int pass = 0; pass < 8; ++pass) {
    int qloc = pass * 4 + l4;
    int phys = l16 ^ (qloc & 7);
    bf16x8 v = *(const bf16x8*)&reg[qloc * 128 + phys * 8];
    int qg = qt * 128 + w * 32 + qloc;
    *(bf16x8*)(AO + (size_t)(b * 2048 + qg) * 4096 + h * 128 + l16 * 8) = v;
  }
}

// ---------- host ----------
extern "C" void kernel_launch(void* const* d_in, const int* in_sizes, int n_in,
                              void* d_out, int out_size, void* d_ws, size_t ws_size,
                              hipStream_t stream) {
  const float* X = (const float*)d_in[0];
  const float* Wq = (const float*)d_in[2];
  const float* Wk = (const float*)d_in[3];
  const float* Wv = (const float*)d_in[4];
  const float* Wo = (const float*)d_in[5];

  char* ws = (char*)d_ws;
  const size_t SEG = 32ull << 20;
  short* Xb  = (short*)(ws + 0 * SEG);
  short* Wqb = (short*)(ws + 1 * SEG);
  short* Wkb = (short*)(ws + 2 * SEG);
  short* Wvb = (short*)(ws + 3 * SEG);
  short* Qb  = (short*)(ws + 4 * SEG);
  short* Kb  = (short*)(ws + 5 * SEG);
  float2* tab = (float2*)(ws + 6 * SEG);  // 1 MiB

  // If the workspace is big enough, convert Wo upfront in the fused cvt (own segment);
  // otherwise fall back to reusing Wkb after the K-GEMM.
  bool bigws = ws_size >= 6 * SEG + (4ull << 20) + SEG;
  short* WobBig = (short*)(ws + 6 * SEG + (4ull << 20));

  const int NE = 4096 * 4096;
  if (bigws) {
    cvt5<<<dim3(2048, 5), 256, 0, stream>>>(X, Wq, Wk, Wv, Wo, Xb, Wqb, Wkb, Wvb, WobBig, NE);
  } else {
    cvt5<<<dim3(2048, 4), 256, 0, stream>>>(X, Wq, Wk, Wv, nullptr, Xb, Wqb, Wkb, Wvb, nullptr, NE);
  }
  rope_table_k<<<512, 256, 0, stream>>>(tab);

  gemm8p<0><<<256, 512, 0, stream>>>(Xb, Wqb, Qb);
  gemm8p<0><<<256, 512, 0, stream>>>(Xb, Wkb, Kb);
  short* Vtb = Wqb;
  gemm8p<2><<<256, 512, 0, stream>>>(Xb, Wvb, Vtb);

  rope_apply_k<<<dim3(4096, 2), 256, 0, stream>>>(Qb, Kb, tab);

  short* AO = Xb;
  attn_k<<<1024, 256, 0, stream>>>(Qb, Kb, Vtb, AO);

  short* Wob;
  if (bigws) {
    Wob = WobBig;
  } else {
    Wob = Wkb;
    cvt_bf16<<<2048, 256, 0, stream>>>(Wo, Wob, NE);
  }
  gemm8p<1><<<256, 512, 0, stream>>>(AO, Wob, (float*)d_out);
}

// Round 9
// 676.290 us; speedup vs baseline: 1.0869x; 1.0869x over previous
//
#include <hip/hip_runtime.h>
#include <stdint.h>

// ---------- types ----------
typedef __attribute__((ext_vector_type(4))) float f32x4;
typedef __attribute__((ext_vector_type(8))) short bf16x8;
typedef __attribute__((ext_vector_type(4))) unsigned int u32x4;

__device__ __forceinline__ short f2bf(float x) {
  unsigned int u = __builtin_bit_cast(unsigned int, x);
  unsigned int r = (u + 0x7fffu + ((u >> 16) & 1u)) >> 16;
  return (short)r;
}
__device__ __forceinline__ float bf2f(short s) {
  unsigned int u = ((unsigned int)(unsigned short)s) << 16;
  return __builtin_bit_cast(float, u);
}
__device__ __forceinline__ unsigned pkbf(float lo, float hi) {
  unsigned r;
  asm("v_cvt_pk_bf16_f32 %0, %1, %2" : "=v"(r) : "v"(lo), "v"(hi));
  return r;
}

__device__ __forceinline__ void gload_lds16(const void* g, void* l) {
  __builtin_amdgcn_global_load_lds(
      (const __attribute__((address_space(1))) void*)g,
      (__attribute__((address_space(3))) void*)l, 16, 0, 0);
}

// ---------- fp32 -> bf16 converts, up to 5 tensors in one launch ----------
__global__ __launch_bounds__(256) void cvt5(const float* __restrict__ a,
                                            const float* __restrict__ b,
                                            const float* __restrict__ c,
                                            const float* __restrict__ d,
                                            const float* __restrict__ e,
                                            short* __restrict__ oa,
                                            short* __restrict__ ob,
                                            short* __restrict__ oc,
                                            short* __restrict__ od,
                                            short* __restrict__ oe, int n) {
  int y = blockIdx.y;
  const float* in = (y == 0) ? a : (y == 1) ? b : (y == 2) ? c : (y == 3) ? d : e;
  short* out = (y == 0) ? oa : (y == 1) ? ob : (y == 2) ? oc : (y == 3) ? od : oe;
  int idx = blockIdx.x * blockDim.x + threadIdx.x;
  int stride = gridDim.x * blockDim.x;
  for (int i = idx * 4; i < n; i += stride * 4) {
    float4 v = *(const float4*)(in + i);
    short4 o;
    o.x = f2bf(v.x); o.y = f2bf(v.y); o.z = f2bf(v.z); o.w = f2bf(v.w);
    *(short4*)(out + i) = o;
  }
}

__global__ __launch_bounds__(256) void cvt_bf16(const float* __restrict__ in,
                                                short* __restrict__ out, int n) {
  int idx = blockIdx.x * blockDim.x + threadIdx.x;
  int stride = gridDim.x * blockDim.x;
  for (int i = idx * 4; i < n; i += stride * 4) {
    float4 v = *(const float4*)(in + i);
    short4 o;
    o.x = f2bf(v.x); o.y = f2bf(v.y); o.z = f2bf(v.z); o.w = f2bf(v.w);
    *(short4*)(out + i) = o;
  }
}

// ---------- RoPE table ----------
__global__ __launch_bounds__(256) void rope_table_k(float2* __restrict__ tab) {
  int idx = blockIdx.x * 256 + threadIdx.x;  // 131072 total
  int s = idx >> 6, j = idx & 63;
  float invf = powf(10000.0f, -((float)j) / 64.0f);
  float a = (float)s * invf;
  tab[idx] = make_float2(cosf(a), sinf(a));
}

// ---------- RoPE apply in-place; Q scaled by log2(e)/sqrt(128) ----------
__global__ __launch_bounds__(256) void rope_apply_k(short* __restrict__ Qb,
                                                    short* __restrict__ Kb,
                                                    const float2* __restrict__ tab) {
  bool isK = (blockIdx.y != 0);
  short* base = isK ? Kb : Qb;
  float post = isK ? 1.0f : (0.08838834764831845f * 1.4426950408889634f);
  int token = blockIdx.x;
  int s = token & 2047;
  short* rowp = base + (size_t)token * 4096;
  const float2* trow = tab + s * 64;
  for (int u = threadIdx.x; u < 512; u += 256) {
    int h = u >> 4;
    int d0 = (u & 15) * 4;
    short* p1 = rowp + h * 128 + d0;
    short* p2 = p1 + 64;
    short4 a = *(short4*)p1, b = *(short4*)p2;
    short4 ra, rb;
#pragma unroll
    for (int j = 0; j < 4; ++j) {
      short aj = (&a.x)[j], bj = (&b.x)[j];
      float qa = bf2f(aj), qb = bf2f(bj);
      float2 cs = trow[d0 + j];
      (&ra.x)[j] = f2bf((qa * cs.x - qb * cs.y) * post);
      (&rb.x)[j] = f2bf((qb * cs.x + qa * cs.y) * post);
    }
    *(short4*)p1 = ra;
    *(short4*)p2 = rb;
  }
}

// ---------- GEMM 256x256 tile, BK=64, 8-phase interleave, counted vmcnt (R7-proven) ----------
template <int MODE>
__global__ __launch_bounds__(512) void gemm8p(const short* __restrict__ A,
                                              const short* __restrict__ Bw,
                                              void* __restrict__ out) {
  __shared__ __attribute__((aligned(16))) short smem[2 * 32768];
  int wg = blockIdx.x;           // 256 blocks = 1 per CU
  int xcd = wg & 7, ii = wg >> 3;
  int by = xcd * 2 + (ii >> 4);
  int bx = ii & 15;
  int tid = threadIdx.x;
  int w = tid >> 6, lane = tid & 63;
  int l16 = lane & 15, l4 = lane >> 4;
  int wm = w >> 2, wn = w & 3;

  f32x4 acc[8][4] = {};

  const short* Ab = A + (size_t)(by * 256) * 4096;
  const short* Bb = Bw + (size_t)(bx * 256) * 4096;

  auto STAGE_MAT = [&](int kt, int isB) {
    const short* src = isB ? Bb : Ab;
    int ob = (kt & 1) * 32768 + isB * 16384;
#pragma unroll
    for (int j = 0; j < 4; ++j) {
      int c = j * 512 + tid;
      int row = c >> 3;
      int sc = (c & 7) ^ (row & 7);
      gload_lds16(src + (size_t)row * 4096 + kt * 64 + sc * 8, &smem[ob + c * 8]);
    }
  };

  bf16x8 bfr[4];
  auto PHASE = [&](int ob, int kk, int mh, bool loadB) {
    const short* lA = &smem[ob];
    const short* lB = &smem[ob + 16384];
    if (loadB) {
#pragma unroll
      for (int nf = 0; nf < 4; ++nf) {
        int row = wn * 64 + nf * 16 + l16;
        int phys = (kk * 4 + l4) ^ (row & 7);
        bfr[nf] = *(const bf16x8*)&lB[row * 64 + phys * 8];
      }
    }
    bf16x8 af[4];
#pragma unroll
    for (int mf = 0; mf < 4; ++mf) {
      int row = wm * 128 + mh * 64 + mf * 16 + l16;
      int phys = (kk * 4 + l4) ^ (row & 7);
      af[mf] = *(const bf16x8*)&lA[row * 64 + phys * 8];
    }
    __builtin_amdgcn_s_setprio(1);
#pragma unroll
    for (int mf = 0; mf < 4; ++mf)
#pragma unroll
      for (int nf = 0; nf < 4; ++nf)
        acc[mh * 4 + mf][nf] =
            __builtin_amdgcn_mfma_f32_16x16x32_bf16(af[mf], bfr[nf], acc[mh * 4 + mf][nf], 0, 0, 0);
    __builtin_amdgcn_s_setprio(0);
    __builtin_amdgcn_s_barrier();
    asm volatile("" ::: "memory");
  };

  STAGE_MAT(0, 0);
  STAGE_MAT(0, 1);
  asm volatile("s_waitcnt vmcnt(0)" ::: "memory");
  __builtin_amdgcn_s_barrier();
  asm volatile("" ::: "memory");

  const int b0 = 0, b1 = 32768;
  for (int i = 0; i < 32; ++i) {
    int kt1 = 2 * i + 1;
    // p0
    STAGE_MAT(kt1, 0);
    asm volatile("s_waitcnt vmcnt(4)" ::: "memory");
    __builtin_amdgcn_s_barrier();
    asm volatile("" ::: "memory");
    PHASE(b0, 0, 0, true);
    // p1
    STAGE_MAT(kt1, 1);
    PHASE(b0, 0, 1, false);
    // p2
    PHASE(b0, 1, 0, true);
    // p3
    PHASE(b0, 1, 1, false);
    // p4
    if (i + 1 < 32) {
      STAGE_MAT(2 * i + 2, 0);
      asm volatile("s_waitcnt vmcnt(4)" ::: "memory");
    } else {
      asm volatile("s_waitcnt vmcnt(0)" ::: "memory");
    }
    __builtin_amdgcn_s_barrier();
    asm volatile("" ::: "memory");
    PHASE(b1, 0, 0, true);
    // p5
    if (i + 1 < 32) STAGE_MAT(2 * i + 2, 1);
    PHASE(b1, 0, 1, false);
    // p6
    PHASE(b1, 1, 0, true);
    // p7
    PHASE(b1, 1, 1, false);
  }

  int orow0 = by * 256 + wm * 128;
  int ocol0 = bx * 256 + wn * 64;
#pragma unroll
  for (int mf = 0; mf < 8; ++mf)
#pragma unroll
    for (int nf = 0; nf < 4; ++nf)
#pragma unroll
      for (int k = 0; k < 4; ++k) {
        int r = orow0 + mf * 16 + l4 * 4 + k;
        int c = ocol0 + nf * 16 + l16;
        float v = acc[mf][nf][k];
        if constexpr (MODE == 0) {
          ((short*)out)[(size_t)r * 4096 + c] = f2bf(v);
        } else if constexpr (MODE == 1) {
          ((float*)out)[(size_t)r * 4096 + c] = v;
        } else {
          int bb = r >> 11, ss = r & 2047;
          int h = c >> 7, d = c & 127;
          ((short*)out)[(((size_t)((bb * 32 + h) * 128 + d)) << 11) + ss] = f2bf(v);
        }
      }
}

// ---------- Flash attention v6: 8 waves x 16 q-rows (low VGPR by construction),
// K dbuf + V single buf (48KB), 2-barrier counted-vmcnt ledger.
// Q pre-scaled by log2e/sqrt(128). Q,K token-major [4096][4096], Vt [64][128][2048].
__global__ __launch_bounds__(512, 4) void attn_k(const short* __restrict__ Qb,
                                                 const short* __restrict__ Kb,
                                                 const short* __restrict__ Vt,
                                                 short* __restrict__ AO) {
  __shared__ __attribute__((aligned(16))) short smem[24576];  // K0 8192 | K1 8192 | V 8192 (shorts)
  int p = blockIdx.x;  // 1024 blocks, qt-major LPT (longest first)
  int bh = p & 63;
  int qt = 15 - (p >> 6);
  int b = bh >> 5, h = bh & 31;
  int tid = threadIdx.x, w = tid >> 6, lane = tid & 63;
  int l16 = lane & 15, l4 = lane >> 4;

  const int nt = 2 * qt + 2;           // >= 2
  const int qbase = qt * 128 + w * 16; // wave owns 16 q rows

  // Q as B-frags: q col = qbase + l16, d = kk*32 + l4*8 + j  (16 VGPR)
  bf16x8 qf[4];
  {
    const short* Qg = Qb + (size_t)(b * 2048 + qbase + l16) * 4096 + h * 128 + l4 * 8;
#pragma unroll
    for (int kk = 0; kk < 4; ++kk) qf[kk] = *(const bf16x8*)(Qg + kk * 32);
  }

  f32x4 oacc[8] = {};  // O^T: d = dg*16 + l4*4 + i, q = l16  (32 VGPR)
  float mrun = -1e30f, lsum = 0.f;

  const short* Kbase = Kb + (size_t)(b * 2048) * 4096 + h * 128;
  const short* Vbase = Vt + (size_t)bh * 128 * 2048;

  auto STAGE_K = [&](int t, int sel) {  // 2 loads/thread, 16KB [64][128] bf16
    short* lK = &smem[sel * 8192];
#pragma unroll
    for (int j = 0; j < 2; ++j) {
      int c = j * 512 + tid;
      int row = c >> 4;
      int src = (c & 15) ^ (row & 15);
      gload_lds16(Kbase + (size_t)(t * 64 + row) * 4096 + src * 8, &lK[c * 8]);
    }
  };
  auto STAGE_V = [&](int t) {  // 2 loads/thread, 16KB [128][64] bf16 (d-major)
    short* lV = &smem[16384];
#pragma unroll
    for (int j = 0; j < 2; ++j) {
      int c = j * 512 + tid;
      int row = c >> 3;
      int src = (c & 7) ^ (row & 7);
      gload_lds16(Vbase + (size_t)row * 2048 + t * 64 + src * 8, &lV[c * 8]);
    }
  };

  // prologue: V(0), K(0), K(1) in flight (6 loads/wave)
  STAGE_V(0);
  STAGE_K(0, 0);
  STAGE_K(1, 1);

  const int src0 = l16 | ((2 * (l4 & 1)) << 4);
  const int src1 = src0 | 16;
  const bool hiA = (l4 >> 1) != 0;

  for (int t = 0; t < nt; ++t) {
    // top: V(t), K(t) landed; K(t+1) may stay in flight
    if (t == nt - 1)
      asm volatile("s_waitcnt vmcnt(0)" ::: "memory");
    else
      asm volatile("s_waitcnt vmcnt(2)" ::: "memory");
    __builtin_amdgcn_s_barrier();
    asm volatile("" ::: "memory");

    bool skip = (t * 64 > qbase + 15);  // tile fully above this wave's diagonal
    if (!skip) {
      const short* lK = &smem[(t & 1) * 8192];
      const short* lV = &smem[16384];

      // S^T = K * Q^T : sacc[n4], kv = n4*16 + l4*4 + i, q = l16  (16 VGPR)
      f32x4 sacc[4] = {};
#pragma unroll
      for (int kk = 0; kk < 4; ++kk) {
#pragma unroll
        for (int n4 = 0; n4 < 4; ++n4) {
          int row = n4 * 16 + l16;
          int phys = (kk * 4 + l4) ^ (row & 15);
          bf16x8 kf = *(const bf16x8*)&lK[row * 128 + phys * 8];
          sacc[n4] = __builtin_amdgcn_mfma_f32_16x16x32_bf16(kf, qf[kk], sacc[n4], 0, 0, 0);
        }
      }

      if (t * 64 + 63 > qbase) {  // diagonal zone: causal mask
        int q = qbase + l16;
#pragma unroll
        for (int n4 = 0; n4 < 4; ++n4)
#pragma unroll
          for (int i = 0; i < 4; ++i) {
            int kv = t * 64 + n4 * 16 + l4 * 4 + i;
            if (kv > q) sacc[n4][i] = -1e30f;
          }
      }

      // online softmax in log2 domain, defer-max (THR=8 -> P <= 256)
      {
        float v0 = fmaxf(fmaxf(sacc[0][0], sacc[0][1]), fmaxf(sacc[0][2], sacc[0][3]));
        float v1 = fmaxf(fmaxf(sacc[1][0], sacc[1][1]), fmaxf(sacc[1][2], sacc[1][3]));
        float v2 = fmaxf(fmaxf(sacc[2][0], sacc[2][1]), fmaxf(sacc[2][2], sacc[2][3]));
        float v3 = fmaxf(fmaxf(sacc[3][0], sacc[3][1]), fmaxf(sacc[3][2], sacc[3][3]));
        float vm = fmaxf(fmaxf(v0, v1), fmaxf(v2, v3));
        vm = fmaxf(vm, __shfl_xor(vm, 16));
        vm = fmaxf(vm, __shfl_xor(vm, 32));
        if (!__all(vm - mrun <= 8.0f)) {
          float mnew = fmaxf(mrun, vm);
          float fsc = __builtin_amdgcn_exp2f(mrun - mnew);
          mrun = mnew;
          lsum *= fsc;
#pragma unroll
          for (int dg = 0; dg < 8; ++dg) oacc[dg] *= fsc;
        }
        float psum = 0.f;
#pragma unroll
        for (int n4 = 0; n4 < 4; ++n4)
#pragma unroll
          for (int i = 0; i < 4; ++i) {
            float e = __builtin_amdgcn_exp2f(sacc[n4][i] - mrun);
            sacc[n4][i] = e;
            psum += e;
          }
        psum += __shfl_xor(psum, 16);
        psum += __shfl_xor(psum, 32);
        lsum += psum;
      }

      // O^T += V^T * P^T, pb built per-c to cap live registers
#pragma unroll
      for (int c = 0; c < 2; ++c) {
        unsigned pk0h0 = pkbf(sacc[2 * c][0], sacc[2 * c][1]);
        unsigned pk0h1 = pkbf(sacc[2 * c][2], sacc[2 * c][3]);
        unsigned pk1h0 = pkbf(sacc[2 * c + 1][0], sacc[2 * c + 1][1]);
        unsigned pk1h1 = pkbf(sacc[2 * c + 1][2], sacc[2 * c + 1][3]);
        unsigned s00 = __shfl((int)pk0h0, src0), s10 = __shfl((int)pk1h0, src0);
        unsigned s01 = __shfl((int)pk0h1, src0), s11 = __shfl((int)pk1h1, src0);
        unsigned t00 = __shfl((int)pk0h0, src1), t10 = __shfl((int)pk1h0, src1);
        unsigned t01 = __shfl((int)pk0h1, src1), t11 = __shfl((int)pk1h1, src1);
        u32x4 uw;
        uw[0] = hiA ? s10 : s00;
        uw[1] = hiA ? s11 : s01;
        uw[2] = hiA ? t10 : t00;
        uw[3] = hiA ? t11 : t01;
        bf16x8 pb = __builtin_bit_cast(bf16x8, uw);
#pragma unroll
        for (int dg = 0; dg < 8; ++dg) {
          int d = dg * 16 + l16;
          int phys = (c * 4 + l4) ^ (l16 & 7);
          bf16x8 vf = *(const bf16x8*)&lV[d * 64 + phys * 8];
          oacc[dg] = __builtin_amdgcn_mfma_f32_16x16x32_bf16(vf, pb, oacc[dg], 0, 0, 0);
        }
      }
    }

    // bottom: all waves done reading K(t), V(t) -> safe to overwrite
    __builtin_amdgcn_s_barrier();
    asm volatile("" ::: "memory");
    if (t + 1 < nt) STAGE_V(t + 1);
    if (t + 2 < nt) STAGE_K(t + 2, t & 1);
  }

  // epilogue: normalize, per-wave LDS transpose O^T -> O (4KB/wave, 32KB total), coalesced store
  __syncthreads();
  short* reg = &smem[w * 2048];
  float rls = 1.0f / lsum;
#pragma unroll
  for (int dg = 0; dg < 8; ++dg) {
    unsigned u0 = pkbf(oacc[dg][0] * rls, oacc[dg][1] * rls);
    unsigned u1 = pkbf(oacc[dg][2] * rls, oacc[dg][3] * rls);
    int cc = dg * 2 + (l4 >> 1);
    int phys = cc ^ l16;  // row = l16, 16-chunk swizzle
    int sidx = l16 * 128 + phys * 8 + (l4 & 1) * 4;
    *(uint2*)&reg[sidx] = make_uint2(u0, u1);
  }
#pragma unroll
  for (int pass = 0; pass < 4; ++pass) {
    int qloc = pass * 4 + l4;
    int phys = l16 ^ qloc;
    bf16x8 v = *(const bf16x8*)&reg[qloc * 128 + phys * 8];
    int tok = b * 2048 + qbase + qloc;
    *(bf16x8*)(AO + (size_t)tok * 4096 + h * 128 + l16 * 8) = v;
  }
}

// ---------- host ----------
extern "C" void kernel_launch(void* const* d_in, const int* in_sizes, int n_in,
                              void* d_out, int out_size, void* d_ws, size_t ws_size,
                              hipStream_t stream) {
  const float* X = (const float*)d_in[0];
  const float* Wq = (const float*)d_in[2];
  const float* Wk = (const float*)d_in[3];
  const float* Wv = (const float*)d_in[4];
  const float* Wo = (const float*)d_in[5];

  char* ws = (char*)d_ws;
  const size_t SEG = 32ull << 20;
  short* Xb  = (short*)(ws + 0 * SEG);
  short* Wqb = (short*)(ws + 1 * SEG);
  short* Wkb = (short*)(ws + 2 * SEG);
  short* Wvb = (short*)(ws + 3 * SEG);
  short* Qb  = (short*)(ws + 4 * SEG);
  short* Kb  = (short*)(ws + 5 * SEG);
  float2* tab = (float2*)(ws + 6 * SEG);  // 1 MiB

  bool bigws = ws_size >= 6 * SEG + (4ull << 20) + SEG;
  short* WobBig = (short*)(ws + 6 * SEG + (4ull << 20));

  const int NE = 4096 * 4096;
  if (bigws) {
    cvt5<<<dim3(2048, 5), 256, 0, stream>>>(X, Wq, Wk, Wv, Wo, Xb, Wqb, Wkb, Wvb, WobBig, NE);
  } else {
    cvt5<<<dim3(2048, 4), 256, 0, stream>>>(X, Wq, Wk, Wv, nullptr, Xb, Wqb, Wkb, Wvb, nullptr, NE);
  }
  rope_table_k<<<512, 256, 0, stream>>>(tab);

  gemm8p<0><<<256, 512, 0, stream>>>(Xb, Wqb, Qb);
  gemm8p<0><<<256, 512, 0, stream>>>(Xb, Wkb, Kb);
  short* Vtb = Wqb;
  gemm8p<2><<<256, 512, 0, stream>>>(Xb, Wvb, Vtb);

  rope_apply_k<<<dim3(4096, 2), 256, 0, stream>>>(Qb, Kb, tab);

  short* AO = Xb;
  attn_k<<<1024, 512, 0, stream>>>(Qb, Kb, Vtb, AO);

  short* Wob;
  if (bigws) {
    Wob = WobBig;
  } else {
    Wob = Wkb;
    cvt_bf16<<<2048, 256, 0, stream>>>(Wo, Wob, NE);
  }
  gemm8p<1><<<256, 512, 0, stream>>>(AO, Wob, (float*)d_out);
}